// Round 1
// baseline (601.037 us; speedup 1.0000x reference)
//
#include <hip/hip_runtime.h>

#define N_NODESC 20000
#define N_EDGESC 1280000
#define CH 256
#define CH4 64

// ---- workspace layout (bytes, all 16B-aligned) ----
constexpr size_t OFF_DEG      = 0;                      // int[20000]
constexpr size_t OFF_ROWSTART = 81920;                  // int[20001]
constexpr size_t OFF_CURSOR   = 163840;                 // int[20000]
constexpr size_t OFF_INVDEG   = 245760;                 // float[20000]
constexpr size_t OFF_ACCUM    = 327680;                 // float[1]
constexpr size_t OFF_CSR      = 331776;                 // int[1280000]
constexpr size_t OFF_MEAN     = OFF_CSR  + 5120000;     // float[20000*256]
constexpr size_t OFF_H1       = OFF_MEAN + 20480000;    // float[20000*256]
constexpr size_t OFF_S1       = OFF_H1   + 20480000;    // float[20000]
constexpr size_t OFF_T1       = OFF_S1   + 80000;       // float[20000]
// total ~46.6 MB

static __device__ __forceinline__ float4 f4add(float4 a, float4 b) {
    return make_float4(a.x + b.x, a.y + b.y, a.z + b.z, a.w + b.w);
}

__global__ void k_zero(int* __restrict__ deg, float* __restrict__ accum) {
    int i = blockIdx.x * blockDim.x + threadIdx.x;
    if (i < N_NODESC) deg[i] = 0;
    if (i == 0) accum[0] = 0.0f;
}

__global__ void k_count(const int* __restrict__ ei, int* __restrict__ deg) {
    int e = blockIdx.x * blockDim.x + threadIdx.x;
    if (e < N_EDGESC) atomicAdd(&deg[ei[N_EDGESC + e]], 1);
}

// single-block exclusive scan over 20000 degrees; also writes cursor copy + inv_deg
__global__ void k_scan(const int* __restrict__ deg, int* __restrict__ row_start,
                       int* __restrict__ cursor, float* __restrict__ inv_deg) {
    __shared__ int sm[1024];
    int carry = 0;
    for (int base = 0; base < N_NODESC; base += 1024) {
        int i = base + (int)threadIdx.x;
        int v = (i < N_NODESC) ? deg[i] : 0;
        sm[threadIdx.x] = v;
        __syncthreads();
        for (int off = 1; off < 1024; off <<= 1) {
            int add = (threadIdx.x >= (unsigned)off) ? sm[threadIdx.x - off] : 0;
            __syncthreads();
            sm[threadIdx.x] += add;
            __syncthreads();
        }
        int incl = sm[threadIdx.x];
        int total = sm[1023];
        if (i < N_NODESC) {
            int excl = carry + incl - v;
            row_start[i] = excl;
            cursor[i]    = excl;
            inv_deg[i]   = 1.0f / (float)max(v, 1);
        }
        carry += total;
        __syncthreads();
    }
    if (threadIdx.x == 0) row_start[N_NODESC] = carry;
}

__global__ void k_fill(const int* __restrict__ ei, int* __restrict__ cursor,
                       int* __restrict__ csr) {
    int e = blockIdx.x * blockDim.x + threadIdx.x;
    if (e < N_EDGESC) {
        int d = ei[N_EDGESC + e];
        int pos = atomicAdd(&cursor[d], 1);
        csr[pos] = ei[e];
    }
}

// one wave per dst node: mean-aggregate 256-ch rows of x
__global__ void __launch_bounds__(256) k_agg1(
        const float4* __restrict__ x4,
        const int* __restrict__ row_start, const int* __restrict__ csr,
        const float* __restrict__ inv_deg, float4* __restrict__ mean4) {
    int wid  = threadIdx.x >> 6;
    int lane = threadIdx.x & 63;
    int node = blockIdx.x * 4 + wid;
    if (node >= N_NODESC) return;
    int start = row_start[node], end = row_start[node + 1];
    float4 a0 = make_float4(0,0,0,0), a1 = make_float4(0,0,0,0);
    float4 a2 = make_float4(0,0,0,0), a3 = make_float4(0,0,0,0);
    for (int j = start; j < end; j += 64) {
        int cnt = min(64, end - j);
        int idx = (lane < cnt) ? csr[j + lane] : 0;
        int k = 0;
        for (; k + 4 <= cnt; k += 4) {
            int s0 = __shfl(idx, k);
            int s1 = __shfl(idx, k + 1);
            int s2 = __shfl(idx, k + 2);
            int s3 = __shfl(idx, k + 3);
            float4 v0 = x4[s0 * CH4 + lane];
            float4 v1 = x4[s1 * CH4 + lane];
            float4 v2 = x4[s2 * CH4 + lane];
            float4 v3 = x4[s3 * CH4 + lane];
            a0 = f4add(a0, v0); a1 = f4add(a1, v1);
            a2 = f4add(a2, v2); a3 = f4add(a3, v3);
        }
        for (; k < cnt; k++) {
            int s0 = __shfl(idx, k);
            a0 = f4add(a0, x4[s0 * CH4 + lane]);
        }
    }
    float inv = inv_deg[node];
    float4 m;
    m.x = (a0.x + a1.x + a2.x + a3.x) * inv;
    m.y = (a0.y + a1.y + a2.y + a3.y) * inv;
    m.z = (a0.z + a1.z + a2.z + a3.z) * inv;
    m.w = (a0.w + a1.w + a2.w + a3.w) * inv;
    mean4[node * CH4 + lane] = m;
}

// h1 = relu([mean|x](20000x512) @ [W1_l|W1_r]^T(512x256) + b1)
#define BM 128
#define BN 64
#define BK 32
__global__ void __launch_bounds__(256) k_gemm1(
        const float4* __restrict__ mean4, const float4* __restrict__ x4,
        const float4* __restrict__ w1l4, const float4* __restrict__ w1r4,
        const float* __restrict__ b1, float4* __restrict__ h14) {
    __shared__ __align__(16) float As[BK][132];  // [k][m], padded
    __shared__ __align__(16) float Bs[BK][68];   // [k][n], padded
    int tx = threadIdx.x & 15;   // n / 4
    int ty = threadIdx.x >> 4;   // m / 8
    int m0 = blockIdx.x * BM;
    int n0 = blockIdx.y * BN;
    float acc[8][4] = {};
    for (int kt = 0; kt < 16; kt++) {
        const float4* Abase = (kt < 8) ? mean4 : x4;
        const float4* Bbase = (kt < 8) ? w1l4  : w1r4;
        int kk0 = (kt & 7) * 8;  // float4 offset within a 256-f row
        // stage A: 128 rows x 32 k  (4 float4 per thread)
        #pragma unroll
        for (int i = 0; i < 4; i++) {
            int f = threadIdx.x + i * 256;
            int row = f >> 3, c4 = f & 7;
            int m = m0 + row;
            float4 v = (m < N_NODESC) ? Abase[m * CH4 + kk0 + c4]
                                      : make_float4(0, 0, 0, 0);
            int k = c4 * 4;
            As[k + 0][row] = v.x; As[k + 1][row] = v.y;
            As[k + 2][row] = v.z; As[k + 3][row] = v.w;
        }
        // stage B: 64 n x 32 k  (2 float4 per thread); B[k][n] = W[n][k]
        #pragma unroll
        for (int i = 0; i < 2; i++) {
            int f = threadIdx.x + i * 256;
            int n = f >> 3, c4 = f & 7;
            float4 v = Bbase[(n0 + n) * CH4 + kk0 + c4];
            int k = c4 * 4;
            Bs[k + 0][n] = v.x; Bs[k + 1][n] = v.y;
            Bs[k + 2][n] = v.z; Bs[k + 3][n] = v.w;
        }
        __syncthreads();
        #pragma unroll
        for (int kk = 0; kk < BK; kk++) {
            float4 a0 = *(const float4*)&As[kk][ty * 8];
            float4 a1 = *(const float4*)&As[kk][ty * 8 + 4];
            float4 b0 = *(const float4*)&Bs[kk][tx * 4];
            float a[8] = {a0.x, a0.y, a0.z, a0.w, a1.x, a1.y, a1.z, a1.w};
            float b[4] = {b0.x, b0.y, b0.z, b0.w};
            #pragma unroll
            for (int i2 = 0; i2 < 8; i2++)
                #pragma unroll
                for (int j2 = 0; j2 < 4; j2++)
                    acc[i2][j2] += a[i2] * b[j2];
        }
        __syncthreads();
    }
    float bb0 = b1[n0 + tx * 4 + 0], bb1 = b1[n0 + tx * 4 + 1];
    float bb2 = b1[n0 + tx * 4 + 2], bb3 = b1[n0 + tx * 4 + 3];
    #pragma unroll
    for (int i2 = 0; i2 < 8; i2++) {
        int m = m0 + ty * 8 + i2;
        if (m < N_NODESC) {
            float4 o;
            o.x = fmaxf(acc[i2][0] + bb0, 0.0f);
            o.y = fmaxf(acc[i2][1] + bb1, 0.0f);
            o.z = fmaxf(acc[i2][2] + bb2, 0.0f);
            o.w = fmaxf(acc[i2][3] + bb3, 0.0f);
            h14[m * CH4 + (n0 >> 2) + tx] = o;
        }
    }
}

// per node: s1 = h1 . w2l ; t1 = h1 . w2r
__global__ void __launch_bounds__(256) k_gemv2(
        const float4* __restrict__ h14, const float4* __restrict__ w2l4,
        const float4* __restrict__ w2r4,
        float* __restrict__ s1, float* __restrict__ t1) {
    int wid = threadIdx.x >> 6, lane = threadIdx.x & 63;
    int node = blockIdx.x * 4 + wid;
    if (node >= N_NODESC) return;
    float4 h  = h14[node * CH4 + lane];
    float4 wl = w2l4[lane];
    float4 wr = w2r4[lane];
    float ds = h.x * wl.x + h.y * wl.y + h.z * wl.z + h.w * wl.w;
    float dt = h.x * wr.x + h.y * wr.y + h.z * wr.z + h.w * wr.w;
    #pragma unroll
    for (int off = 32; off > 0; off >>= 1) {
        ds += __shfl_down(ds, off);
        dt += __shfl_down(dt, off);
    }
    if (lane == 0) { s1[node] = ds; t1[node] = dt; }
}

// per node: scalar segment-sum of s1 over in-edges, layer2 epilogue, fc dot
__global__ void __launch_bounds__(256) k_layer2(
        const int* __restrict__ row_start, const int* __restrict__ csr,
        const float* __restrict__ inv_deg, const float* __restrict__ s1,
        const float* __restrict__ t1, const float* __restrict__ b2,
        const float* __restrict__ fc_w, float* __restrict__ accum) {
    __shared__ float part[4];
    int wid = threadIdx.x >> 6, lane = threadIdx.x & 63;
    int node = blockIdx.x * 4 + wid;
    float contrib = 0.0f;
    if (node < N_NODESC) {
        int start = row_start[node], end = row_start[node + 1];
        float s = 0.0f;
        for (int j = start + lane; j < end; j += 64) s += s1[csr[j]];
        #pragma unroll
        for (int off = 32; off > 0; off >>= 1) s += __shfl_down(s, off);
        if (lane == 0) {
            float h2 = fmaxf(s * inv_deg[node] + b2[0] + t1[node], 0.0f);
            contrib = h2 * fc_w[node];
        }
    }
    if (lane == 0) part[wid] = contrib;
    __syncthreads();
    if (threadIdx.x == 0) {
        atomicAdd(accum, part[0] + part[1] + part[2] + part[3]);
    }
}

__global__ void k_final(const float* __restrict__ accum,
                        const float* __restrict__ fc_b, float* __restrict__ out) {
    out[0] = accum[0] + fc_b[0];
}

extern "C" void kernel_launch(void* const* d_in, const int* in_sizes, int n_in,
                              void* d_out, int out_size, void* d_ws, size_t ws_size,
                              hipStream_t stream) {
    const float* x    = (const float*)d_in[0];
    const int*   ei   = (const int*)d_in[1];
    const float* w1l  = (const float*)d_in[2];
    const float* b1   = (const float*)d_in[3];
    const float* w1r  = (const float*)d_in[4];
    const float* w2l  = (const float*)d_in[5];
    const float* b2   = (const float*)d_in[6];
    const float* w2r  = (const float*)d_in[7];
    const float* fcw  = (const float*)d_in[8];
    const float* fcb  = (const float*)d_in[9];
    float* out = (float*)d_out;

    char* ws = (char*)d_ws;
    int*   deg       = (int*)(ws + OFF_DEG);
    int*   row_start = (int*)(ws + OFF_ROWSTART);
    int*   cursor    = (int*)(ws + OFF_CURSOR);
    float* inv_deg   = (float*)(ws + OFF_INVDEG);
    float* accum     = (float*)(ws + OFF_ACCUM);
    int*   csr       = (int*)(ws + OFF_CSR);
    float* meanb     = (float*)(ws + OFF_MEAN);
    float* h1        = (float*)(ws + OFF_H1);
    float* s1        = (float*)(ws + OFF_S1);
    float* t1        = (float*)(ws + OFF_T1);

    k_zero<<<79, 256, 0, stream>>>(deg, accum);
    k_count<<<5000, 256, 0, stream>>>(ei, deg);
    k_scan<<<1, 1024, 0, stream>>>(deg, row_start, cursor, inv_deg);
    k_fill<<<5000, 256, 0, stream>>>(ei, cursor, csr);
    k_agg1<<<5000, 256, 0, stream>>>((const float4*)x, row_start, csr, inv_deg,
                                     (float4*)meanb);
    dim3 ggrid(157, 4);
    k_gemm1<<<ggrid, 256, 0, stream>>>((const float4*)meanb, (const float4*)x,
                                       (const float4*)w1l, (const float4*)w1r,
                                       b1, (float4*)h1);
    k_gemv2<<<5000, 256, 0, stream>>>((const float4*)h1, (const float4*)w2l,
                                      (const float4*)w2r, s1, t1);
    k_layer2<<<5000, 256, 0, stream>>>(row_start, csr, inv_deg, s1, t1, b2,
                                       fcw, accum);
    k_final<<<1, 1, 0, stream>>>(accum, fcb, out);
}

// Round 2
// 487.159 us; speedup vs baseline: 1.2338x; 1.2338x over previous
//
#include <hip/hip_runtime.h>

#define N_NODESC 20000
#define N_EDGESC 1280000
#define CH 256
#define CH4 64

// ---- workspace layout (bytes, all 16B-aligned) ----
constexpr size_t OFF_DEG      = 0;                      // int[20000]
constexpr size_t OFF_ROWSTART = 81920;                  // int[20001]
constexpr size_t OFF_CURSOR   = 163840;                 // int[20000]
constexpr size_t OFF_INVDEG   = 245760;                 // float[20000]
constexpr size_t OFF_ACCUM    = 327680;                 // float[1]
constexpr size_t OFF_BSUM     = 327696;                 // int[128]
constexpr size_t OFF_BOFF     = 328208;                 // int[128]
constexpr size_t OFF_CSR      = 331776;                 // int[1280000]
constexpr size_t OFF_MEAN     = OFF_CSR  + 5120000;     // float[20000*256]
constexpr size_t OFF_S1       = OFF_MEAN + 20480000;    // float[20000]
constexpr size_t OFF_T1       = OFF_S1   + 80000;       // float[20000]

static __device__ __forceinline__ float4 f4add(float4 a, float4 b) {
    return make_float4(a.x + b.x, a.y + b.y, a.z + b.z, a.w + b.w);
}

__global__ void k_zero(int* __restrict__ deg, float* __restrict__ s1,
                       float* __restrict__ t1, float* __restrict__ accum) {
    int i = blockIdx.x * blockDim.x + threadIdx.x;
    if (i < N_NODESC) { deg[i] = 0; s1[i] = 0.0f; t1[i] = 0.0f; }
    if (i == 0) accum[0] = 0.0f;
}

__global__ void k_count(const int* __restrict__ ei, int* __restrict__ deg) {
    int e = blockIdx.x * blockDim.x + threadIdx.x;
    if (e < N_EDGESC) atomicAdd(&deg[ei[N_EDGESC + e]], 1);
}

// --- 3-phase scan: block sums -> scan of block sums -> per-block scan ---
__global__ void __launch_bounds__(256) k_scan1(const int* __restrict__ deg,
                                               int* __restrict__ bsum) {
    __shared__ int sm[4];
    int i = blockIdx.x * 256 + threadIdx.x;
    int v = (i < N_NODESC) ? deg[i] : 0;
    #pragma unroll
    for (int off = 32; off > 0; off >>= 1) v += __shfl_down(v, off);
    if ((threadIdx.x & 63) == 0) sm[threadIdx.x >> 6] = v;
    __syncthreads();
    if (threadIdx.x == 0) bsum[blockIdx.x] = sm[0] + sm[1] + sm[2] + sm[3];
}

__global__ void k_scan2(const int* __restrict__ bsum, int* __restrict__ boff,
                        int* __restrict__ row_start) {
    __shared__ int sm[128];
    int t = threadIdx.x;
    int v = (t < 79) ? bsum[t] : 0;
    sm[t] = v;
    __syncthreads();
    for (int off = 1; off < 128; off <<= 1) {
        int add = (t >= off) ? sm[t - off] : 0;
        __syncthreads();
        sm[t] += add;
        __syncthreads();
    }
    if (t < 79) boff[t] = sm[t] - v;
    if (t == 0) row_start[N_NODESC] = sm[127];
}

__global__ void __launch_bounds__(256) k_scan3(
        const int* __restrict__ deg, const int* __restrict__ boff,
        int* __restrict__ row_start, int* __restrict__ cursor,
        float* __restrict__ inv_deg) {
    __shared__ int wsum[4];
    int i = blockIdx.x * 256 + threadIdx.x;
    int lane = threadIdx.x & 63, wid = threadIdx.x >> 6;
    int v = (i < N_NODESC) ? deg[i] : 0;
    int incl = v;
    #pragma unroll
    for (int off = 1; off < 64; off <<= 1) {
        int n = __shfl_up(incl, off);
        if (lane >= off) incl += n;
    }
    if (lane == 63) wsum[wid] = incl;
    __syncthreads();
    int wpre = 0;
    #pragma unroll
    for (int w = 0; w < 4; w++) wpre += (w < wid) ? wsum[w] : 0;
    if (i < N_NODESC) {
        int excl = boff[blockIdx.x] + wpre + incl - v;
        row_start[i] = excl;
        cursor[i]    = excl;
        inv_deg[i]   = 1.0f / (float)max(v, 1);
    }
}

__global__ void k_fill(const int* __restrict__ ei, int* __restrict__ cursor,
                       int* __restrict__ csr) {
    int e = blockIdx.x * blockDim.x + threadIdx.x;
    if (e < N_EDGESC) {
        int d = ei[N_EDGESC + e];
        int pos = atomicAdd(&cursor[d], 1);
        csr[pos] = ei[e];
    }
}

// one wave per (dst node, 32-channel chunk); chunk = blockIdx.x & 7 -> XCD
// working set per chunk = 20000*32*4 = 2.56 MB < 4 MB per-XCD L2
__global__ void __launch_bounds__(256) k_agg1(
        const float4* __restrict__ x4,
        const int* __restrict__ row_start, const int* __restrict__ csr,
        const float* __restrict__ inv_deg, float4* __restrict__ mean4) {
    int wid   = threadIdx.x >> 6;
    int lane  = threadIdx.x & 63;
    int chunk = blockIdx.x & 7;
    int node  = (blockIdx.x >> 3) * 4 + wid;
    if (node >= N_NODESC) return;
    int c4 = lane & 7;             // float4 within the 32-ch chunk
    int eg = lane >> 3;            // edge subgroup 0..7
    int cbase = chunk * 8 + c4;
    int start = row_start[node], end = row_start[node + 1];
    float4 acc = make_float4(0, 0, 0, 0);
    int j = start;
    for (; j + 64 <= end; j += 64) {
        int idx = __builtin_nontemporal_load(&csr[j + lane]);
        #pragma unroll
        for (int k = 0; k < 8; k++) {
            int src = __shfl(idx, k * 8 + eg);
            acc = f4add(acc, x4[src * CH4 + cbase]);
        }
    }
    int rem = end - j;
    if (rem > 0) {
        int idx = (lane < rem) ? __builtin_nontemporal_load(&csr[j + lane]) : 0;
        #pragma unroll
        for (int k = 0; k < 8; k++) {
            int e = k * 8 + eg;
            int src = __shfl(idx, e);
            if (e < rem) acc = f4add(acc, x4[src * CH4 + cbase]);
        }
    }
    // reduce across the 8 edge subgroups (xor bits 3..5 of lane)
    #pragma unroll
    for (int off = 8; off < 64; off <<= 1) {
        acc.x += __shfl_xor(acc.x, off);
        acc.y += __shfl_xor(acc.y, off);
        acc.z += __shfl_xor(acc.z, off);
        acc.w += __shfl_xor(acc.w, off);
    }
    if (eg == 0) {
        float inv = inv_deg[node];
        mean4[node * CH4 + cbase] =
            make_float4(acc.x * inv, acc.y * inv, acc.z * inv, acc.w * inv);
    }
}

// h1 = relu([mean|x](20000x512) @ [W1_l|W1_r]^T(512x256) + b1)
// fused epilogue: s1[m] += h1[m,:].w2l ; t1[m] += h1[m,:].w2r  (h1 never stored)
#define BM 128
#define BN 64
#define BK 32
__global__ void __launch_bounds__(256) k_gemm1(
        const float4* __restrict__ mean4, const float4* __restrict__ x4,
        const float4* __restrict__ w1l4, const float4* __restrict__ w1r4,
        const float* __restrict__ b1, const float* __restrict__ w2l,
        const float* __restrict__ w2r,
        float* __restrict__ s1, float* __restrict__ t1) {
    __shared__ __align__(16) float As[BK][132];  // [k][m], padded
    __shared__ __align__(16) float Bs[BK][68];   // [k][n], padded
    int tx = threadIdx.x & 15;   // n / 4
    int ty = threadIdx.x >> 4;   // m / 8
    int m0 = blockIdx.x * BM;
    int n0 = blockIdx.y * BN;
    float acc[8][4] = {};
    for (int kt = 0; kt < 16; kt++) {
        const float4* Abase = (kt < 8) ? mean4 : x4;
        const float4* Bbase = (kt < 8) ? w1l4  : w1r4;
        int kk0 = (kt & 7) * 8;
        #pragma unroll
        for (int i = 0; i < 4; i++) {
            int f = threadIdx.x + i * 256;
            int row = f >> 3, c4 = f & 7;
            int m = m0 + row;
            float4 v = (m < N_NODESC) ? Abase[m * CH4 + kk0 + c4]
                                      : make_float4(0, 0, 0, 0);
            int k = c4 * 4;
            As[k + 0][row] = v.x; As[k + 1][row] = v.y;
            As[k + 2][row] = v.z; As[k + 3][row] = v.w;
        }
        #pragma unroll
        for (int i = 0; i < 2; i++) {
            int f = threadIdx.x + i * 256;
            int n = f >> 3, c4 = f & 7;
            float4 v = Bbase[(n0 + n) * CH4 + kk0 + c4];
            int k = c4 * 4;
            Bs[k + 0][n] = v.x; Bs[k + 1][n] = v.y;
            Bs[k + 2][n] = v.z; Bs[k + 3][n] = v.w;
        }
        __syncthreads();
        #pragma unroll
        for (int kk = 0; kk < BK; kk++) {
            float4 a0 = *(const float4*)&As[kk][ty * 8];
            float4 a1 = *(const float4*)&As[kk][ty * 8 + 4];
            float4 b0 = *(const float4*)&Bs[kk][tx * 4];
            float a[8] = {a0.x, a0.y, a0.z, a0.w, a1.x, a1.y, a1.z, a1.w};
            float b[4] = {b0.x, b0.y, b0.z, b0.w};
            #pragma unroll
            for (int i2 = 0; i2 < 8; i2++)
                #pragma unroll
                for (int j2 = 0; j2 < 4; j2++)
                    acc[i2][j2] += a[i2] * b[j2];
        }
        __syncthreads();
    }
    int nb = n0 + tx * 4;
    float bb0 = b1[nb + 0], bb1 = b1[nb + 1], bb2 = b1[nb + 2], bb3 = b1[nb + 3];
    float wl0 = w2l[nb + 0], wl1 = w2l[nb + 1], wl2 = w2l[nb + 2], wl3 = w2l[nb + 3];
    float wr0 = w2r[nb + 0], wr1 = w2r[nb + 1], wr2 = w2r[nb + 2], wr3 = w2r[nb + 3];
    #pragma unroll
    for (int i2 = 0; i2 < 8; i2++) {
        int m = m0 + ty * 8 + i2;
        float o0 = fmaxf(acc[i2][0] + bb0, 0.0f);
        float o1 = fmaxf(acc[i2][1] + bb1, 0.0f);
        float o2 = fmaxf(acc[i2][2] + bb2, 0.0f);
        float o3 = fmaxf(acc[i2][3] + bb3, 0.0f);
        float ps = o0 * wl0 + o1 * wl1 + o2 * wl2 + o3 * wl3;
        float pt = o0 * wr0 + o1 * wr1 + o2 * wr2 + o3 * wr3;
        #pragma unroll
        for (int off = 8; off > 0; off >>= 1) {
            ps += __shfl_down(ps, off, 16);
            pt += __shfl_down(pt, off, 16);
        }
        if (tx == 0 && m < N_NODESC) {
            atomicAdd(&s1[m], ps);
            atomicAdd(&t1[m], pt);
        }
    }
}

// per node: scalar segment-sum of s1 over in-edges, layer2 epilogue, fc dot
__global__ void __launch_bounds__(256) k_layer2(
        const int* __restrict__ row_start, const int* __restrict__ csr,
        const float* __restrict__ inv_deg, const float* __restrict__ s1,
        const float* __restrict__ t1, const float* __restrict__ b2,
        const float* __restrict__ fc_w, float* __restrict__ accum) {
    __shared__ float part[4];
    int wid = threadIdx.x >> 6, lane = threadIdx.x & 63;
    int node = blockIdx.x * 4 + wid;
    float contrib = 0.0f;
    if (node < N_NODESC) {
        int start = row_start[node], end = row_start[node + 1];
        float s = 0.0f;
        for (int j = start + lane; j < end; j += 64) s += s1[csr[j]];
        #pragma unroll
        for (int off = 32; off > 0; off >>= 1) s += __shfl_down(s, off);
        if (lane == 0) {
            float h2 = fmaxf(s * inv_deg[node] + b2[0] + t1[node], 0.0f);
            contrib = h2 * fc_w[node];
        }
    }
    if (lane == 0) part[wid] = contrib;
    __syncthreads();
    if (threadIdx.x == 0) {
        atomicAdd(accum, part[0] + part[1] + part[2] + part[3]);
    }
}

__global__ void k_final(const float* __restrict__ accum,
                        const float* __restrict__ fc_b, float* __restrict__ out) {
    out[0] = accum[0] + fc_b[0];
}

extern "C" void kernel_launch(void* const* d_in, const int* in_sizes, int n_in,
                              void* d_out, int out_size, void* d_ws, size_t ws_size,
                              hipStream_t stream) {
    const float* x    = (const float*)d_in[0];
    const int*   ei   = (const int*)d_in[1];
    const float* w1l  = (const float*)d_in[2];
    const float* b1   = (const float*)d_in[3];
    const float* w1r  = (const float*)d_in[4];
    const float* w2l  = (const float*)d_in[5];
    const float* b2   = (const float*)d_in[6];
    const float* w2r  = (const float*)d_in[7];
    const float* fcw  = (const float*)d_in[8];
    const float* fcb  = (const float*)d_in[9];
    float* out = (float*)d_out;

    char* ws = (char*)d_ws;
    int*   deg       = (int*)(ws + OFF_DEG);
    int*   row_start = (int*)(ws + OFF_ROWSTART);
    int*   cursor    = (int*)(ws + OFF_CURSOR);
    float* inv_deg   = (float*)(ws + OFF_INVDEG);
    float* accum     = (float*)(ws + OFF_ACCUM);
    int*   bsum      = (int*)(ws + OFF_BSUM);
    int*   boff      = (int*)(ws + OFF_BOFF);
    int*   csr       = (int*)(ws + OFF_CSR);
    float* meanb     = (float*)(ws + OFF_MEAN);
    float* s1        = (float*)(ws + OFF_S1);
    float* t1        = (float*)(ws + OFF_T1);

    k_zero<<<79, 256, 0, stream>>>(deg, s1, t1, accum);
    k_count<<<5000, 256, 0, stream>>>(ei, deg);
    k_scan1<<<79, 256, 0, stream>>>(deg, bsum);
    k_scan2<<<1, 128, 0, stream>>>(bsum, boff, row_start);
    k_scan3<<<79, 256, 0, stream>>>(deg, boff, row_start, cursor, inv_deg);
    k_fill<<<5000, 256, 0, stream>>>(ei, cursor, csr);
    k_agg1<<<40000, 256, 0, stream>>>((const float4*)x, row_start, csr, inv_deg,
                                      (float4*)meanb);
    dim3 ggrid(157, 4);
    k_gemm1<<<ggrid, 256, 0, stream>>>((const float4*)meanb, (const float4*)x,
                                       (const float4*)w1l, (const float4*)w1r,
                                       b1, w2l, w2r, s1, t1);
    k_layer2<<<5000, 256, 0, stream>>>(row_start, csr, inv_deg, s1, t1, b2,
                                       fcw, accum);
    k_final<<<1, 1, 0, stream>>>(accum, fcb, out);
}